// Round 3
// baseline (370.586 us; speedup 1.0000x reference)
//
#include <hip/hip_runtime.h>
#include <math.h>

#define B_   32
#define L_   4096
#define IN_  1024
#define QS_  64
#define VS_  256
#define H_   16
#define CL_  128
#define NCH_ 32

// workspace layout (float offsets), total 17.04 MB
#define Q_OFF   0
#define M_OFF   32768
#define S_OFF   (M_OFF + B_ * NCH_ * H_)
#define CTX_OFF (S_OFF + B_ * NCH_ * H_)

__device__ __forceinline__ float dot4(float4 a, float4 b) {
    return a.x*b.x + a.y*b.y + a.z*b.z + a.w*b.w;
}

// ---------------------------------------------------------------------------
// Kernel A: q[b,c] = (query[b,:] . Wq[c,:] + bq[c]) / 8
// 16-way k-split per output: 2048 blocks x 256 thr (8 blocks/CU).
// ---------------------------------------------------------------------------
__global__ __launch_bounds__(256) void qproj_kernel(
        const float* __restrict__ query, const float* __restrict__ Wq,
        const float* __restrict__ bq, float* __restrict__ ws) {
    const int t = threadIdx.x;
    const int g = blockIdx.x * 256 + t;
    const int o = g >> 4, sub = g & 15;      // 16 threads per output
    const int b = o >> 10, c = o & 1023;

    const float4* wq4 = (const float4*)(Wq + (size_t)c * IN_) + sub * 16;
    const float4* q4  = (const float4*)(query + (size_t)b * IN_) + sub * 16;
    float4 acc = make_float4(0.f, 0.f, 0.f, 0.f);
    #pragma unroll
    for (int k = 0; k < 16; ++k) {
        float4 w = wq4[k], q = q4[k];
        acc.x += w.x * q.x; acc.y += w.y * q.y;
        acc.z += w.z * q.z; acc.w += w.w * q.w;
    }
    float r = acc.x + acc.y + acc.z + acc.w;
    r += __shfl_xor(r, 1);
    r += __shfl_xor(r, 2);
    r += __shfl_xor(r, 4);
    r += __shfl_xor(r, 8);
    if (sub == 0) ws[Q_OFF + b * 1024 + c] = (r + bq[c]) * 0.125f;
}

// ---------------------------------------------------------------------------
// Kernel B: per (b, chunk of 128 rows): 8 waves, wave w owns heads 2w,2w+1
// over ALL rows. grid (32, 32) x 512 thr -> 4 blocks/CU, 32 waves/CU.
// ---------------------------------------------------------------------------
__global__ __launch_bounds__(512, 8) void attn_chunk_kernel(
        const float* __restrict__ key, const float* __restrict__ value,
        float* __restrict__ ws) {
    __shared__ float4 qs4[256];        // q[h][e4]     (4 KB)
    __shared__ float2 ps2[8 * CL_];    // per-wave p   (8 KB)

    const int t  = threadIdx.x;
    const int ch = blockIdx.x, b = blockIdx.y;
    const int lm = t & 63, w = t >> 6;          // w in 0..7
    const int l0 = ch * CL_;

    if (t < 256) qs4[t] = ((const float4*)(ws + Q_OFF + (size_t)b * IN_))[t];
    __syncthreads();

    // ---- Phase A: scores. lane owns rows 2lm, 2lm+1; wave's 2 heads.
    const float* keyb = key + ((size_t)b * L_ + l0) * QS_;
    float s[2][2] = {{0.f, 0.f}, {0.f, 0.f}};
    #pragma unroll
    for (int e4 = 0; e4 < 16; ++e4) {
        float4 q0 = qs4[(2 * w) * 16 + e4];
        float4 q1 = qs4[(2 * w + 1) * 16 + e4];
        #pragma unroll
        for (int j = 0; j < 2; ++j) {
            float4 kv = *(const float4*)(keyb + (size_t)(2 * lm + j) * QS_ + e4 * 4);
            s[j][0] += dot4(kv, q0);
            s[j][1] += dot4(kv, q1);
        }
    }

    // wave-local max / exp / sum per head
    float m[2], sum[2], p[2][2];
    #pragma unroll
    for (int hh = 0; hh < 2; ++hh) {
        float v = fmaxf(s[0][hh], s[1][hh]);
        #pragma unroll
        for (int off = 32; off >= 1; off >>= 1) v = fmaxf(v, __shfl_xor(v, off));
        m[hh] = v;
    }
    #pragma unroll
    for (int j = 0; j < 2; ++j)
        #pragma unroll
        for (int hh = 0; hh < 2; ++hh) p[j][hh] = __expf(s[j][hh] - m[hh]);
    #pragma unroll
    for (int hh = 0; hh < 2; ++hh) {
        float v = p[0][hh] + p[1][hh];
        #pragma unroll
        for (int off = 32; off >= 1; off >>= 1) v += __shfl_xor(v, off);
        sum[hh] = v;
    }
    if (lm == 0) {
        #pragma unroll
        for (int hh = 0; hh < 2; ++hh) {
            ws[M_OFF + (b * NCH_ + ch) * H_ + 2 * w + hh] = m[hh];
            ws[S_OFF + (b * NCH_ + ch) * H_ + 2 * w + hh] = sum[hh];
        }
    }

    // stash p (wave-local region; same-wave ds ordering via lgkmcnt)
    #pragma unroll
    for (int j = 0; j < 2; ++j)
        ps2[w * CL_ + 2 * lm + j] = make_float2(p[j][0], p[j][1]);

    // ---- Phase B: ctx[hh][e] = sum_l p[l][hh] * value[l][e]
    float4 ctx0 = make_float4(0.f, 0.f, 0.f, 0.f);
    float4 ctx1 = make_float4(0.f, 0.f, 0.f, 0.f);
    const float*  valb = value + ((size_t)b * L_ + l0) * VS_;
    const float2* psw  = ps2 + w * CL_;
    for (int i0 = 0; i0 < CL_; i0 += 4) {
        float4 vv[4]; float2 pv[4];
        #pragma unroll
        for (int u = 0; u < 4; ++u)
            vv[u] = *(const float4*)(valb + (size_t)(i0 + u) * VS_ + 4 * lm);
        #pragma unroll
        for (int u = 0; u < 4; ++u) pv[u] = psw[i0 + u];
        #pragma unroll
        for (int u = 0; u < 4; ++u) {
            ctx0.x += pv[u].x * vv[u].x; ctx0.y += pv[u].x * vv[u].y;
            ctx0.z += pv[u].x * vv[u].z; ctx0.w += pv[u].x * vv[u].w;
            ctx1.x += pv[u].y * vv[u].x; ctx1.y += pv[u].y * vv[u].y;
            ctx1.z += pv[u].y * vv[u].z; ctx1.w += pv[u].y * vv[u].w;
        }
    }

    float* ctxw = ws + CTX_OFF + (size_t)((b * NCH_ + ch) * H_) * VS_;
    *(float4*)(ctxw + (size_t)(2 * w) * VS_ + 4 * lm)     = ctx0;
    *(float4*)(ctxw + (size_t)(2 * w + 1) * VS_ + 4 * lm) = ctx1;
}

// ---------------------------------------------------------------------------
// Kernel C: flash-combine chunk partials + project with Wv + bias.
// ---------------------------------------------------------------------------
__global__ __launch_bounds__(256) void reduce_proj_kernel(
        const float* __restrict__ Wv, const float* __restrict__ bv,
        const float* __restrict__ ws, float* __restrict__ out) {
    __shared__ __align__(16) float ctx_lds[VS_];
    const int t = threadIdx.x;
    const int b = blockIdx.x >> 4, h = blockIdx.x & 15;

    float M = -1e30f;
    #pragma unroll
    for (int c = 0; c < NCH_; ++c)
        M = fmaxf(M, ws[M_OFF + (b * NCH_ + c) * H_ + h]);

    float S = 0.f, acc = 0.f;
    #pragma unroll 4
    for (int c = 0; c < NCH_; ++c) {
        float wgt = __expf(ws[M_OFF + (b * NCH_ + c) * H_ + h] - M);
        S += ws[S_OFF + (b * NCH_ + c) * H_ + h] * wgt;
        acc += wgt * ws[CTX_OFF + ((size_t)(b * NCH_ + c) * H_ + h) * VS_ + t];
    }
    ctx_lds[t] = acc / S;
    __syncthreads();

    const int d = t >> 2, qq = t & 3;
    const float4* wv4 = (const float4*)(Wv + (size_t)(h * 64 + d) * VS_);
    const float4* cl4 = (const float4*)ctx_lds;
    float a = 0.f;
    #pragma unroll
    for (int i = 0; i < 16; ++i) a += dot4(wv4[qq * 16 + i], cl4[qq * 16 + i]);
    a += __shfl_xor(a, 1);
    a += __shfl_xor(a, 2);
    if (qq == 0) out[b * 1024 + h * 64 + d] = a + bv[h * 64 + d];
}

extern "C" void kernel_launch(void* const* d_in, const int* in_sizes, int n_in,
                              void* d_out, int out_size, void* d_ws, size_t ws_size,
                              hipStream_t stream) {
    (void)in_sizes; (void)n_in; (void)out_size; (void)ws_size;
    const float* query = (const float*)d_in[0];
    const float* key   = (const float*)d_in[1];
    const float* value = (const float*)d_in[2];
    const float* Wq    = (const float*)d_in[3];
    const float* bq    = (const float*)d_in[4];
    const float* Wv    = (const float*)d_in[5];
    const float* bv    = (const float*)d_in[6];
    float* out = (float*)d_out;
    float* ws  = (float*)d_ws;

    qproj_kernel<<<2048, 256, 0, stream>>>(query, Wq, bq, ws);
    attn_chunk_kernel<<<dim3(NCH_, B_), 512, 0, stream>>>(key, value, ws);
    reduce_proj_kernel<<<B_ * H_, 256, 0, stream>>>(Wv, bv, ws, out);
}

// Round 4
// 260.575 us; speedup vs baseline: 1.4222x; 1.4222x over previous
//
#include <hip/hip_runtime.h>
#include <math.h>

#define B_   32
#define L_   4096
#define IN_  1024
#define QS_  64
#define VS_  256
#define H_   16
#define CL_  128
#define NCH_ 32

// workspace layout (float offsets), total 17.04 MB
#define Q_OFF   0
#define M_OFF   32768
#define S_OFF   (M_OFF + B_ * NCH_ * H_)
#define CTX_OFF (S_OFF + B_ * NCH_ * H_)

__device__ __forceinline__ float dot4(float4 a, float4 b) {
    return a.x*b.x + a.y*b.y + a.z*b.z + a.w*b.w;
}

// ---------------------------------------------------------------------------
// Kernel A: q[b,c] = (query[b,:] . Wq[c,:] + bq[c]) / 8
// One wave per output row: 64 lanes x 4 coalesced float4 loads, shfl reduce.
// grid 8192 x 256 thr.
// ---------------------------------------------------------------------------
__global__ __launch_bounds__(256) void qproj_kernel(
        const float* __restrict__ query, const float* __restrict__ Wq,
        const float* __restrict__ bq, float* __restrict__ ws) {
    const int t = threadIdx.x;
    const int lm = t & 63, w = t >> 6;
    const int o = blockIdx.x * 4 + w;          // output index in [0, 32768)
    const int b = o >> 10, c = o & 1023;

    const float4* wq4 = (const float4*)(Wq + (size_t)c * IN_);
    const float4* q4  = (const float4*)(query + (size_t)b * IN_);
    float4 acc = make_float4(0.f, 0.f, 0.f, 0.f);
    #pragma unroll
    for (int j = 0; j < 4; ++j) {
        float4 wv = wq4[j * 64 + lm];
        float4 qv = q4[j * 64 + lm];
        acc.x += wv.x * qv.x; acc.y += wv.y * qv.y;
        acc.z += wv.z * qv.z; acc.w += wv.w * qv.w;
    }
    float r = acc.x + acc.y + acc.z + acc.w;
    #pragma unroll
    for (int off = 32; off >= 1; off >>= 1) r += __shfl_xor(r, off);
    if (lm == 0) ws[Q_OFF + b * 1024 + c] = (r + bq[c]) * 0.125f;
}

// ---------------------------------------------------------------------------
// Kernel B: per (b, chunk of 128 rows): 4 waves, wave w owns heads 4w..4w+3
// over ALL rows (R2-proven shape). Phase B is 8-deep software-pipelined.
// grid (32, 32) x 256 thr.
// ---------------------------------------------------------------------------
__global__ __launch_bounds__(256, 4) void attn_chunk_kernel(
        const float* __restrict__ key, const float* __restrict__ value,
        float* __restrict__ ws) {
    __shared__ float4 qs4[256];        // q[h][e4]     (4 KB)
    __shared__ float4 ps4[4 * CL_];    // per-wave p   (8 KB)

    const int t  = threadIdx.x;
    const int ch = blockIdx.x, b = blockIdx.y;
    const int lm = t & 63, w = t >> 6;
    const int l0 = ch * CL_;

    qs4[t] = ((const float4*)(ws + Q_OFF + (size_t)b * IN_))[t];
    __syncthreads();

    // ---- Phase A: scores. lane owns rows 2lm, 2lm+1; wave's 4 heads.
    const float* keyb = key + ((size_t)b * L_ + l0) * QS_;
    float s[2][4];
    #pragma unroll
    for (int j = 0; j < 2; ++j)
        #pragma unroll
        for (int hh = 0; hh < 4; ++hh) s[j][hh] = 0.f;

    #pragma unroll
    for (int e4 = 0; e4 < 16; ++e4) {
        float4 qv[4];
        #pragma unroll
        for (int hh = 0; hh < 4; ++hh) qv[hh] = qs4[(4 * w + hh) * 16 + e4];
        #pragma unroll
        for (int j = 0; j < 2; ++j) {
            float4 kv = *(const float4*)(keyb + (size_t)(2 * lm + j) * QS_ + e4 * 4);
            #pragma unroll
            for (int hh = 0; hh < 4; ++hh) s[j][hh] += dot4(kv, qv[hh]);
        }
    }

    // wave-local max / exp / sum per head
    float m[4], sum[4], p[2][4];
    #pragma unroll
    for (int hh = 0; hh < 4; ++hh) {
        float v = fmaxf(s[0][hh], s[1][hh]);
        #pragma unroll
        for (int off = 32; off >= 1; off >>= 1) v = fmaxf(v, __shfl_xor(v, off));
        m[hh] = v;
    }
    #pragma unroll
    for (int j = 0; j < 2; ++j)
        #pragma unroll
        for (int hh = 0; hh < 4; ++hh) p[j][hh] = __expf(s[j][hh] - m[hh]);
    #pragma unroll
    for (int hh = 0; hh < 4; ++hh) {
        float v = p[0][hh] + p[1][hh];
        #pragma unroll
        for (int off = 32; off >= 1; off >>= 1) v += __shfl_xor(v, off);
        sum[hh] = v;
    }
    if (lm == 0) {
        #pragma unroll
        for (int hh = 0; hh < 4; ++hh) {
            ws[M_OFF + (b * NCH_ + ch) * H_ + 4 * w + hh] = m[hh];
            ws[S_OFF + (b * NCH_ + ch) * H_ + 4 * w + hh] = sum[hh];
        }
    }

    // stash p (wave-local region; same-wave LDS ordering via lgkmcnt)
    #pragma unroll
    for (int j = 0; j < 2; ++j)
        ps4[w * CL_ + 2 * lm + j] = make_float4(p[j][0], p[j][1], p[j][2], p[j][3]);

    // ---- Phase B: ctx[hh][e] = sum_l p[l][hh] * value[l][e]
    // lane owns e = 4*lm..4*lm+3; 8-deep double-buffered value prefetch.
    float4 ctx0 = make_float4(0.f,0.f,0.f,0.f), ctx1 = ctx0;
    float4 ctx2 = ctx0, ctx3 = ctx0;
    const float*  valb = value + ((size_t)b * L_ + l0) * VS_;
    const float4* psw  = ps4 + w * CL_;

    float4 vv[8];
    #pragma unroll
    for (int u = 0; u < 8; ++u)
        vv[u] = *(const float4*)(valb + (size_t)u * VS_ + 4 * lm);

    for (int i0 = 0; i0 < CL_ - 8; i0 += 8) {
        float4 nv[8];
        #pragma unroll
        for (int u = 0; u < 8; ++u)
            nv[u] = *(const float4*)(valb + (size_t)(i0 + 8 + u) * VS_ + 4 * lm);
        #pragma unroll
        for (int u = 0; u < 8; ++u) {
            float4 pu = psw[i0 + u];
            ctx0.x += pu.x * vv[u].x; ctx0.y += pu.x * vv[u].y;
            ctx0.z += pu.x * vv[u].z; ctx0.w += pu.x * vv[u].w;
            ctx1.x += pu.y * vv[u].x; ctx1.y += pu.y * vv[u].y;
            ctx1.z += pu.y * vv[u].z; ctx1.w += pu.y * vv[u].w;
            ctx2.x += pu.z * vv[u].x; ctx2.y += pu.z * vv[u].y;
            ctx2.z += pu.z * vv[u].z; ctx2.w += pu.z * vv[u].w;
            ctx3.x += pu.w * vv[u].x; ctx3.y += pu.w * vv[u].y;
            ctx3.z += pu.w * vv[u].z; ctx3.w += pu.w * vv[u].w;
        }
        #pragma unroll
        for (int u = 0; u < 8; ++u) vv[u] = nv[u];
    }
    #pragma unroll
    for (int u = 0; u < 8; ++u) {
        float4 pu = psw[CL_ - 8 + u];
        ctx0.x += pu.x * vv[u].x; ctx0.y += pu.x * vv[u].y;
        ctx0.z += pu.x * vv[u].z; ctx0.w += pu.x * vv[u].w;
        ctx1.x += pu.y * vv[u].x; ctx1.y += pu.y * vv[u].y;
        ctx1.z += pu.y * vv[u].z; ctx1.w += pu.y * vv[u].w;
        ctx2.x += pu.z * vv[u].x; ctx2.y += pu.z * vv[u].y;
        ctx2.z += pu.z * vv[u].z; ctx2.w += pu.z * vv[u].w;
        ctx3.x += pu.w * vv[u].x; ctx3.y += pu.w * vv[u].y;
        ctx3.z += pu.w * vv[u].z; ctx3.w += pu.w * vv[u].w;
    }

    float* ctxw = ws + CTX_OFF + (size_t)((b * NCH_ + ch) * H_) * VS_;
    *(float4*)(ctxw + (size_t)(4 * w + 0) * VS_ + 4 * lm) = ctx0;
    *(float4*)(ctxw + (size_t)(4 * w + 1) * VS_ + 4 * lm) = ctx1;
    *(float4*)(ctxw + (size_t)(4 * w + 2) * VS_ + 4 * lm) = ctx2;
    *(float4*)(ctxw + (size_t)(4 * w + 3) * VS_ + 4 * lm) = ctx3;
}

// ---------------------------------------------------------------------------
// Kernel C: flash-combine chunk partials + project with Wv + bias.
// All 32 ctx loads issued as one independent batch (MLP), m/s via LDS.
// ---------------------------------------------------------------------------
__global__ __launch_bounds__(256) void reduce_proj_kernel(
        const float* __restrict__ Wv, const float* __restrict__ bv,
        const float* __restrict__ ws, float* __restrict__ out) {
    __shared__ float m_l[NCH_], s_l[NCH_];
    __shared__ __align__(16) float ctx_lds[VS_];
    const int t = threadIdx.x;
    const int b = blockIdx.x >> 4, h = blockIdx.x & 15;

    if (t < NCH_)
        m_l[t] = ws[M_OFF + (b * NCH_ + t) * H_ + h];
    else if (t < 2 * NCH_)
        s_l[t - NCH_] = ws[S_OFF + (b * NCH_ + (t - NCH_)) * H_ + h];
    __syncthreads();

    float M = -1e30f;
    #pragma unroll
    for (int c = 0; c < NCH_; ++c) M = fmaxf(M, m_l[c]);

    float wgt[NCH_];
    float S = 0.f;
    #pragma unroll
    for (int c = 0; c < NCH_; ++c) {
        wgt[c] = __expf(m_l[c] - M);
        S += s_l[c] * wgt[c];
    }

    float tmp[NCH_];
    #pragma unroll
    for (int c = 0; c < NCH_; ++c)
        tmp[c] = ws[CTX_OFF + ((size_t)(b * NCH_ + c) * H_ + h) * VS_ + t];
    float acc = 0.f;
    #pragma unroll
    for (int c = 0; c < NCH_; ++c) acc += wgt[c] * tmp[c];

    ctx_lds[t] = acc / S;
    __syncthreads();

    const int d = t >> 2, qq = t & 3;
    const float4* wv4 = (const float4*)(Wv + (size_t)(h * 64 + d) * VS_);
    const float4* cl4 = (const float4*)ctx_lds;
    float a = 0.f;
    #pragma unroll
    for (int i = 0; i < 16; ++i) a += dot4(wv4[qq * 16 + i], cl4[qq * 16 + i]);
    a += __shfl_xor(a, 1);
    a += __shfl_xor(a, 2);
    if (qq == 0) out[b * 1024 + h * 64 + d] = a + bv[h * 64 + d];
}

extern "C" void kernel_launch(void* const* d_in, const int* in_sizes, int n_in,
                              void* d_out, int out_size, void* d_ws, size_t ws_size,
                              hipStream_t stream) {
    (void)in_sizes; (void)n_in; (void)out_size; (void)ws_size;
    const float* query = (const float*)d_in[0];
    const float* key   = (const float*)d_in[1];
    const float* value = (const float*)d_in[2];
    const float* Wq    = (const float*)d_in[3];
    const float* bq    = (const float*)d_in[4];
    const float* Wv    = (const float*)d_in[5];
    const float* bv    = (const float*)d_in[6];
    float* out = (float*)d_out;
    float* ws  = (float*)d_ws;

    qproj_kernel<<<8192, 256, 0, stream>>>(query, Wq, bq, ws);
    attn_chunk_kernel<<<dim3(NCH_, B_), 256, 0, stream>>>(key, value, ws);
    reduce_proj_kernel<<<B_ * H_, 256, 0, stream>>>(Wv, bv, ws, out);
}

// Round 5
// 257.023 us; speedup vs baseline: 1.4418x; 1.0138x over previous
//
#include <hip/hip_runtime.h>
#include <math.h>

#define B_   32
#define L_   4096
#define IN_  1024
#define QS_  64
#define VS_  256
#define H_   16
#define CL_  128
#define NCH_ 32

// workspace layout (float offsets), total 17.04 MB
#define Q_OFF   0
#define M_OFF   32768
#define S_OFF   (M_OFF + B_ * NCH_ * H_)
#define CTX_OFF (S_OFF + B_ * NCH_ * H_)

__device__ __forceinline__ float dot4(float4 a, float4 b) {
    return a.x*b.x + a.y*b.y + a.z*b.z + a.w*b.w;
}

// ---------------------------------------------------------------------------
// Kernel A: q[b,c] = (query[b,:] . Wq[c,:] + bq[c]) / 8
// One wave per output row: 64 lanes x 4 coalesced float4 loads, shfl reduce.
// ---------------------------------------------------------------------------
__global__ __launch_bounds__(256) void qproj_kernel(
        const float* __restrict__ query, const float* __restrict__ Wq,
        const float* __restrict__ bq, float* __restrict__ ws) {
    const int t = threadIdx.x;
    const int lm = t & 63, w = t >> 6;
    const int o = blockIdx.x * 4 + w;
    const int b = o >> 10, c = o & 1023;

    const float4* wq4 = (const float4*)(Wq + (size_t)c * IN_);
    const float4* q4  = (const float4*)(query + (size_t)b * IN_);
    float4 acc = make_float4(0.f, 0.f, 0.f, 0.f);
    #pragma unroll
    for (int j = 0; j < 4; ++j) {
        float4 wv = wq4[j * 64 + lm];
        float4 qv = q4[j * 64 + lm];
        acc.x += wv.x * qv.x; acc.y += wv.y * qv.y;
        acc.z += wv.z * qv.z; acc.w += wv.w * qv.w;
    }
    float r = acc.x + acc.y + acc.z + acc.w;
    #pragma unroll
    for (int off = 32; off >= 1; off >>= 1) r += __shfl_xor(r, off);
    if (lm == 0) ws[Q_OFF + b * 1024 + c] = (r + bq[c]) * 0.125f;
}

// ---------------------------------------------------------------------------
// Kernel B: per (b, chunk of 128 rows): 4 waves, wave w owns heads 4w..4w+3.
// Phase B: value staged block-cooperatively through double-buffered LDS
// (8-row / 8 KB tiles), consumed via conflict-free ds_read_b128.
// ---------------------------------------------------------------------------
__global__ __launch_bounds__(256, 4) void attn_chunk_kernel(
        const float* __restrict__ key, const float* __restrict__ value,
        float* __restrict__ ws) {
    __shared__ float4 qs4[256];                       // 4 KB  q[h][e4]
    __shared__ float4 ps4[4 * CL_];                   // 8 KB  per-wave p
    __shared__ __align__(16) float vbuf[2][8][VS_];   // 16 KB value tiles

    const int t  = threadIdx.x;
    const int ch = blockIdx.x, b = blockIdx.y;
    const int lm = t & 63, w = t >> 6;
    const int l0 = ch * CL_;

    qs4[t] = ((const float4*)(ws + Q_OFF + (size_t)b * IN_))[t];
    __syncthreads();

    // ---- Phase A: scores. lane owns rows 2lm, 2lm+1; wave's 4 heads.
    const float* keyb = key + ((size_t)b * L_ + l0) * QS_;
    float s[2][4];
    #pragma unroll
    for (int j = 0; j < 2; ++j)
        #pragma unroll
        for (int hh = 0; hh < 4; ++hh) s[j][hh] = 0.f;

    #pragma unroll
    for (int e4 = 0; e4 < 16; ++e4) {
        float4 qv[4];
        #pragma unroll
        for (int hh = 0; hh < 4; ++hh) qv[hh] = qs4[(4 * w + hh) * 16 + e4];
        #pragma unroll
        for (int j = 0; j < 2; ++j) {
            float4 kv = *(const float4*)(keyb + (size_t)(2 * lm + j) * QS_ + e4 * 4);
            #pragma unroll
            for (int hh = 0; hh < 4; ++hh) s[j][hh] += dot4(kv, qv[hh]);
        }
    }

    // wave-local max / exp / sum per head
    float m[4], sum[4], p[2][4];
    #pragma unroll
    for (int hh = 0; hh < 4; ++hh) {
        float v = fmaxf(s[0][hh], s[1][hh]);
        #pragma unroll
        for (int off = 32; off >= 1; off >>= 1) v = fmaxf(v, __shfl_xor(v, off));
        m[hh] = v;
    }
    #pragma unroll
    for (int j = 0; j < 2; ++j)
        #pragma unroll
        for (int hh = 0; hh < 4; ++hh) p[j][hh] = __expf(s[j][hh] - m[hh]);
    #pragma unroll
    for (int hh = 0; hh < 4; ++hh) {
        float v = p[0][hh] + p[1][hh];
        #pragma unroll
        for (int off = 32; off >= 1; off >>= 1) v += __shfl_xor(v, off);
        sum[hh] = v;
    }
    if (lm == 0) {
        #pragma unroll
        for (int hh = 0; hh < 4; ++hh) {
            ws[M_OFF + (b * NCH_ + ch) * H_ + 4 * w + hh] = m[hh];
            ws[S_OFF + (b * NCH_ + ch) * H_ + 4 * w + hh] = sum[hh];
        }
    }

    // stash p (wave-local region; same-wave LDS ordering via lgkmcnt)
    #pragma unroll
    for (int j = 0; j < 2; ++j)
        ps4[w * CL_ + 2 * lm + j] = make_float4(p[j][0], p[j][1], p[j][2], p[j][3]);

    // ---- Phase B: ctx[hh][e] = sum_l p[l][hh] * value[l][e]
    // 16 tiles of 8 rows. Stage: 256 thr x 2 float4 (coalesced 4 KB/instr).
    // Consume: each wave reads all 8 rows from LDS (2-way = conflict-free).
    float4 ctx0 = make_float4(0.f,0.f,0.f,0.f), ctx1 = ctx0, ctx2 = ctx0, ctx3 = ctx0;
    const float4* valb4 = (const float4*)(value + ((size_t)b * L_ + l0) * VS_);
    const float4* psw   = ps4 + w * CL_;

    // prologue: stage tile 0 into buf 0
    {
        float4 r0 = valb4[t], r1 = valb4[256 + t];
        ((float4*)vbuf[0])[t]       = r0;
        ((float4*)vbuf[0])[256 + t] = r1;
    }

    #define CONSUME(cb, tl)                                                    \
        _Pragma("unroll")                                                      \
        for (int rr = 0; rr < 8; ++rr) {                                       \
            float4 vv = *(const float4*)&vbuf[cb][rr][4 * lm];                 \
            float4 pu = psw[(tl) * 8 + rr];                                    \
            ctx0.x += pu.x * vv.x; ctx0.y += pu.x * vv.y;                      \
            ctx0.z += pu.x * vv.z; ctx0.w += pu.x * vv.w;                      \
            ctx1.x += pu.y * vv.x; ctx1.y += pu.y * vv.y;                      \
            ctx1.z += pu.y * vv.z; ctx1.w += pu.y * vv.w;                      \
            ctx2.x += pu.z * vv.x; ctx2.y += pu.z * vv.y;                      \
            ctx2.z += pu.z * vv.z; ctx2.w += pu.z * vv.w;                      \
            ctx3.x += pu.w * vv.x; ctx3.y += pu.w * vv.y;                      \
            ctx3.z += pu.w * vv.z; ctx3.w += pu.w * vv.w;                      \
        }

    for (int tl = 0; tl < 15; ++tl) {
        __syncthreads();                       // buf[tl&1] ready
        const int cb = tl & 1, nb = cb ^ 1;
        float4 n0 = valb4[(size_t)(tl + 1) * 512 + t];        // issue next-tile
        float4 n1 = valb4[(size_t)(tl + 1) * 512 + 256 + t];  // loads early
        CONSUME(cb, tl)                        // 128 FMA hides load latency
        ((float4*)vbuf[nb])[t]       = n0;     // implicit vmcnt wait here
        ((float4*)vbuf[nb])[256 + t] = n1;
    }
    __syncthreads();
    CONSUME(1, 15)
    #undef CONSUME

    float* ctxw = ws + CTX_OFF + (size_t)((b * NCH_ + ch) * H_) * VS_;
    *(float4*)(ctxw + (size_t)(4 * w + 0) * VS_ + 4 * lm) = ctx0;
    *(float4*)(ctxw + (size_t)(4 * w + 1) * VS_ + 4 * lm) = ctx1;
    *(float4*)(ctxw + (size_t)(4 * w + 2) * VS_ + 4 * lm) = ctx2;
    *(float4*)(ctxw + (size_t)(4 * w + 3) * VS_ + 4 * lm) = ctx3;
}

// ---------------------------------------------------------------------------
// Kernel C: flash-combine chunk partials + project with Wv + bias.
// ---------------------------------------------------------------------------
__global__ __launch_bounds__(256) void reduce_proj_kernel(
        const float* __restrict__ Wv, const float* __restrict__ bv,
        const float* __restrict__ ws, float* __restrict__ out) {
    __shared__ float m_l[NCH_], s_l[NCH_];
    __shared__ __align__(16) float ctx_lds[VS_];
    const int t = threadIdx.x;
    const int b = blockIdx.x >> 4, h = blockIdx.x & 15;

    if (t < NCH_)
        m_l[t] = ws[M_OFF + (b * NCH_ + t) * H_ + h];
    else if (t < 2 * NCH_)
        s_l[t - NCH_] = ws[S_OFF + (b * NCH_ + (t - NCH_)) * H_ + h];
    __syncthreads();

    float M = -1e30f;
    #pragma unroll
    for (int c = 0; c < NCH_; ++c) M = fmaxf(M, m_l[c]);

    float wgt[NCH_];
    float S = 0.f;
    #pragma unroll
    for (int c = 0; c < NCH_; ++c) {
        wgt[c] = __expf(m_l[c] - M);
        S += s_l[c] * wgt[c];
    }

    float tmp[NCH_];
    #pragma unroll
    for (int c = 0; c < NCH_; ++c)
        tmp[c] = ws[CTX_OFF + ((size_t)(b * NCH_ + c) * H_ + h) * VS_ + t];
    float acc = 0.f;
    #pragma unroll
    for (int c = 0; c < NCH_; ++c) acc += wgt[c] * tmp[c];

    ctx_lds[t] = acc / S;
    __syncthreads();

    const int d = t >> 2, qq = t & 3;
    const float4* wv4 = (const float4*)(Wv + (size_t)(h * 64 + d) * VS_);
    const float4* cl4 = (const float4*)ctx_lds;
    float a = 0.f;
    #pragma unroll
    for (int i = 0; i < 16; ++i) a += dot4(wv4[qq * 16 + i], cl4[qq * 16 + i]);
    a += __shfl_xor(a, 1);
    a += __shfl_xor(a, 2);
    if (qq == 0) out[b * 1024 + h * 64 + d] = a + bv[h * 64 + d];
}

extern "C" void kernel_launch(void* const* d_in, const int* in_sizes, int n_in,
                              void* d_out, int out_size, void* d_ws, size_t ws_size,
                              hipStream_t stream) {
    (void)in_sizes; (void)n_in; (void)out_size; (void)ws_size;
    const float* query = (const float*)d_in[0];
    const float* key   = (const float*)d_in[1];
    const float* value = (const float*)d_in[2];
    const float* Wq    = (const float*)d_in[3];
    const float* bq    = (const float*)d_in[4];
    const float* Wv    = (const float*)d_in[5];
    const float* bv    = (const float*)d_in[6];
    float* out = (float*)d_out;
    float* ws  = (float*)d_ws;

    qproj_kernel<<<8192, 256, 0, stream>>>(query, Wq, bq, ws);
    attn_chunk_kernel<<<dim3(NCH_, B_), 256, 0, stream>>>(key, value, ws);
    reduce_proj_kernel<<<B_ * H_, 256, 0, stream>>>(Wv, bv, ws, out);
}